// Round 2
// baseline (223.169 us; speedup 1.0000x reference)
//
#include <hip/hip_runtime.h>
#include <math.h>

#define NPTS 2048
#define BLOCK 256
#define WPB 4              // waves per block; one wave handles one batch element
#define ITERS 8            // 8 iters x 64 lanes x 4 points = 2048 points

// Accumulators: 0-2 sum(p), 3-5 sum(c), 6 sum|p|^2, 7 sum|c|^2,
// 8-16 sum p_j*c_k (row-major 3x3).
__global__ __launch_bounds__(BLOCK, 4) void kabsch_kernel(
    const float* __restrict__ P, const float* __restrict__ C,
    float* __restrict__ rmsd_out, int B) {
  const int wave = threadIdx.x >> 6;
  const int lane = threadIdx.x & 63;
  const int b = blockIdx.x * WPB + wave;
  if (b >= B) return;

  const float4* p4 = (const float4*)(P + (size_t)b * (NPTS * 3));
  const float4* c4 = (const float4*)(C + (size_t)b * (NPTS * 3));

  float acc[17];
#pragma unroll
  for (int i = 0; i < 17; i++) acc[i] = 0.f;

  // Each iteration: wave covers 256 points = 192 float4 per tensor.
  // Lane reads 3 consecutive float4 (4 whole points). Depth-2 prefetch.
  int base = 3 * lane;
  float4 pa = p4[base], pb = p4[base + 1], pq = p4[base + 2];
  float4 ca = c4[base], cb = c4[base + 1], cq = c4[base + 2];

#pragma unroll
  for (int k = 0; k < ITERS; k++) {
    float4 npa, npb, npq, nca, ncb, ncq;
    if (k < ITERS - 1) {
      const int nb_ = base + 192;
      npa = p4[nb_]; npb = p4[nb_ + 1]; npq = p4[nb_ + 2];
      nca = c4[nb_]; ncb = c4[nb_ + 1]; ncq = c4[nb_ + 2];
    }
    const float Px[4] = {pa.x, pa.w, pb.z, pq.y};
    const float Py[4] = {pa.y, pb.x, pb.w, pq.z};
    const float Pz[4] = {pa.z, pb.y, pq.x, pq.w};
    const float Cx[4] = {ca.x, ca.w, cb.z, cq.y};
    const float Cy[4] = {ca.y, cb.x, cb.w, cq.z};
    const float Cz[4] = {ca.z, cb.y, cq.x, cq.w};
#pragma unroll
    for (int i = 0; i < 4; i++) {
      const float px = Px[i], py = Py[i], pz = Pz[i];
      const float cx = Cx[i], cy = Cy[i], cz = Cz[i];
      acc[0] += px; acc[1] += py; acc[2] += pz;
      acc[3] += cx; acc[4] += cy; acc[5] += cz;
      acc[6] += px * px + py * py + pz * pz;
      acc[7] += cx * cx + cy * cy + cz * cz;
      acc[8]  += px * cx; acc[9]  += px * cy; acc[10] += px * cz;
      acc[11] += py * cx; acc[12] += py * cy; acc[13] += py * cz;
      acc[14] += pz * cx; acc[15] += pz * cy; acc[16] += pz * cz;
    }
    pa = npa; pb = npb; pq = npq;
    ca = nca; cb = ncb; cq = ncq;
    base += 192;
  }

  // wave-level butterfly reduction (64 lanes); no cross-wave step needed
#pragma unroll
  for (int off = 32; off > 0; off >>= 1) {
#pragma unroll
    for (int i = 0; i < 17; i++) acc[i] += __shfl_down(acc[i], off);
  }

  if (lane == 0) {
    double s[17];
#pragma unroll
    for (int i = 0; i < 17; i++) s[i] = (double)acc[i];
    const double invN = 1.0 / (double)NPTS;
    const double spx = s[0], spy = s[1], spz = s[2];
    const double scx = s[3], scy = s[4], scz = s[5];
    const double Ep = s[6] - (spx * spx + spy * spy + spz * spz) * invN;
    const double Ec = s[7] - (scx * scx + scy * scy + scz * scz) * invN;
    const double a00 = s[8]  - spx * scx * invN, a01 = s[9]  - spx * scy * invN, a02 = s[10] - spx * scz * invN;
    const double a10 = s[11] - spy * scx * invN, a11 = s[12] - spy * scy * invN, a12 = s[13] - spy * scz * invN;
    const double a20 = s[14] - spz * scx * invN, a21 = s[15] - spz * scy * invN, a22 = s[16] - spz * scz * invN;
    const double det = a00 * (a11 * a22 - a12 * a21)
                     - a01 * (a10 * a22 - a12 * a20)
                     + a02 * (a10 * a21 - a11 * a20);
    // Gram matrix G = A^T A; singular values = sqrt(eig(G)) via Cardano
    const double b00 = a00 * a00 + a10 * a10 + a20 * a20;
    const double b11 = a01 * a01 + a11 * a11 + a21 * a21;
    const double b22 = a02 * a02 + a12 * a12 + a22 * a22;
    const double b01 = a00 * a01 + a10 * a11 + a20 * a21;
    const double b02 = a00 * a02 + a10 * a12 + a20 * a22;
    const double b12 = a01 * a02 + a11 * a12 + a21 * a22;
    const double q = (b00 + b11 + b22) / 3.0;
    const double p1 = b01 * b01 + b02 * b02 + b12 * b12;
    const double d0 = b00 - q, d1 = b11 - q, d2 = b22 - q;
    const double p2 = d0 * d0 + d1 * d1 + d2 * d2 + 2.0 * p1;
    double e1, e2, e3;
    if (p2 < 1e-30) {
      e1 = e2 = e3 = q;
    } else {
      const double pp = sqrt(p2 / 6.0);
      const double inv = 1.0 / pp;
      const double c00 = d0 * inv, c11 = d1 * inv, c22 = d2 * inv;
      const double c01 = b01 * inv, c02 = b02 * inv, c12 = b12 * inv;
      double r = 0.5 * (c00 * (c11 * c22 - c12 * c12)
                      - c01 * (c01 * c22 - c12 * c02)
                      + c02 * (c01 * c12 - c11 * c02));
      r = fmin(1.0, fmax(-1.0, r));
      const double phi = acos(r) / 3.0;
      e1 = q + 2.0 * pp * cos(phi);
      e3 = q + 2.0 * pp * cos(phi + 2.0943951023931953);
      e2 = 3.0 * q - e1 - e3;
    }
    const double s1 = sqrt(fmax(e1, 0.0));
    const double s2 = sqrt(fmax(e2, 0.0));
    const double s3 = sqrt(fmax(e3, 0.0));
    const double dsign = (det > 0.0) ? 1.0 : ((det < 0.0) ? -1.0 : 0.0);
    const double trRS = s1 + s2 + dsign * s3;
    const double msd = (Ep + Ec - 2.0 * trRS) * invN;
    rmsd_out[b] = (float)sqrt(fmax(msd, 0.0));
  }
}

// Reduce B per-batch RMSDs -> mean, single block.
__global__ __launch_bounds__(BLOCK) void mean_kernel(
    const float* __restrict__ rmsd, float* __restrict__ out, int B) {
  float s = 0.f;
  for (int i = threadIdx.x; i < B; i += BLOCK) s += rmsd[i];
#pragma unroll
  for (int off = 32; off > 0; off >>= 1) s += __shfl_down(s, off);
  __shared__ float sm[BLOCK / 64];
  const int wave = threadIdx.x >> 6, lane = threadIdx.x & 63;
  if (lane == 0) sm[wave] = s;
  __syncthreads();
  if (threadIdx.x == 0) {
    float tot = 0.f;
    for (int w = 0; w < BLOCK / 64; w++) tot += sm[w];
    out[0] = tot / (float)B;
  }
}

extern "C" void kernel_launch(void* const* d_in, const int* in_sizes, int n_in,
                              void* d_out, int out_size, void* d_ws, size_t ws_size,
                              hipStream_t stream) {
  const float* P = (const float*)d_in[0];
  const float* C = (const float*)d_in[1];
  float* out = (float*)d_out;
  float* ws = (float*)d_ws;  // B floats of per-batch RMSD
  const int B = in_sizes[0] / (NPTS * 3);
  const int grid = (B + WPB - 1) / WPB;
  kabsch_kernel<<<grid, BLOCK, 0, stream>>>(P, C, ws, B);
  mean_kernel<<<1, BLOCK, 0, stream>>>(ws, out, B);
}

// Round 3
// 219.166 us; speedup vs baseline: 1.0183x; 1.0183x over previous
//
#include <hip/hip_runtime.h>
#include <math.h>

#define NPTS 2048
#define NF4 (NPTS * 3 / 4)    // 1536 float4 per tensor per batch
#define BLOCK 256
#define CHUNKS (NF4 / BLOCK)  // 6 async 16B loads per thread per tensor
#define PPT (NPTS / BLOCK)    // 8 points per thread

// One block per batch. Stage whole batch (24 KB x 2) into LDS with
// global_load_lds dwordx4 (perfect coalescing, deep MLP, no VGPR roundtrip),
// then accumulate the 17 Kabsch sums from LDS (12 B lane stride = 2-way bank
// aliasing = free), wave-shuffle reduce, float Cardano epilogue.
__global__ __launch_bounds__(BLOCK, 3) void kabsch_kernel(
    const float* __restrict__ P, const float* __restrict__ C,
    float* __restrict__ rmsd_out, int B) {
  __shared__ float4 sP[NF4];
  __shared__ float4 sC[NF4];
  __shared__ float red[BLOCK / 64][17];

  const int b = blockIdx.x;
  const int t = threadIdx.x;
  const float4* p4 = (const float4*)(P + (size_t)b * (NPTS * 3));
  const float4* c4 = (const float4*)(C + (size_t)b * (NPTS * 3));

  // Async global -> LDS stage. LDS dest per (chunk, wave) is wave-uniform
  // base + lane*16, exactly the HW constraint for global_load_lds.
#pragma unroll
  for (int c = 0; c < CHUNKS; c++) {
    const int idx = c * BLOCK + t;
    __builtin_amdgcn_global_load_lds(
        (const __attribute__((address_space(1))) void*)(p4 + idx),
        (__attribute__((address_space(3))) void*)(&sP[idx]), 16, 0, 0);
    __builtin_amdgcn_global_load_lds(
        (const __attribute__((address_space(1))) void*)(c4 + idx),
        (__attribute__((address_space(3))) void*)(&sC[idx]), 16, 0, 0);
  }
  __syncthreads();  // compiler emits s_waitcnt vmcnt(0) before s_barrier

  const float* Pf = (const float*)sP;
  const float* Cf = (const float*)sC;

  // acc: 0-2 sum(p), 3-5 sum(c), 6 sum|p|^2, 7 sum|c|^2, 8-16 sum p_j*c_k
  float acc[17];
#pragma unroll
  for (int i = 0; i < 17; i++) acc[i] = 0.f;

#pragma unroll
  for (int k = 0; k < PPT; k++) {
    const int pt = k * BLOCK + t;  // striped: lane stride 12 B, conflict-free
    const float px = Pf[3 * pt], py = Pf[3 * pt + 1], pz = Pf[3 * pt + 2];
    const float cx = Cf[3 * pt], cy = Cf[3 * pt + 1], cz = Cf[3 * pt + 2];
    acc[0] += px; acc[1] += py; acc[2] += pz;
    acc[3] += cx; acc[4] += cy; acc[5] += cz;
    acc[6] += px * px + py * py + pz * pz;
    acc[7] += cx * cx + cy * cy + cz * cz;
    acc[8]  += px * cx; acc[9]  += px * cy; acc[10] += px * cz;
    acc[11] += py * cx; acc[12] += py * cy; acc[13] += py * cz;
    acc[14] += pz * cx; acc[15] += pz * cy; acc[16] += pz * cz;
  }

  // wave (64-lane) butterfly reduce, then 4-wave combine via LDS
#pragma unroll
  for (int off = 32; off > 0; off >>= 1) {
#pragma unroll
    for (int i = 0; i < 17; i++) acc[i] += __shfl_down(acc[i], off);
  }
  const int wave = t >> 6, lane = t & 63;
  if (lane == 0) {
#pragma unroll
    for (int i = 0; i < 17; i++) red[wave][i] = acc[i];
  }
  __syncthreads();

  if (t == 0) {
    float s[17];
#pragma unroll
    for (int i = 0; i < 17; i++)
      s[i] = red[0][i] + red[1][i] + red[2][i] + red[3][i];
    const float invN = 1.0f / (float)NPTS;
    const float spx = s[0], spy = s[1], spz = s[2];
    const float scx = s[3], scy = s[4], scz = s[5];
    const float Ep = s[6] - (spx * spx + spy * spy + spz * spz) * invN;
    const float Ec = s[7] - (scx * scx + scy * scy + scz * scz) * invN;
    // centered cross-covariance A (3x3)
    const float a00 = s[8]  - spx * scx * invN, a01 = s[9]  - spx * scy * invN, a02 = s[10] - spx * scz * invN;
    const float a10 = s[11] - spy * scx * invN, a11 = s[12] - spy * scy * invN, a12 = s[13] - spy * scz * invN;
    const float a20 = s[14] - spz * scx * invN, a21 = s[15] - spz * scy * invN, a22 = s[16] - spz * scz * invN;
    const float det = a00 * (a11 * a22 - a12 * a21)
                    - a01 * (a10 * a22 - a12 * a20)
                    + a02 * (a10 * a21 - a11 * a20);
    // G = A^T A (sym PSD); singular values = sqrt(eig(G)) via Cardano
    const float b00 = a00 * a00 + a10 * a10 + a20 * a20;
    const float b11 = a01 * a01 + a11 * a11 + a21 * a21;
    const float b22 = a02 * a02 + a12 * a12 + a22 * a22;
    const float b01 = a00 * a01 + a10 * a11 + a20 * a21;
    const float b02 = a00 * a02 + a10 * a12 + a20 * a22;
    const float b12 = a01 * a02 + a11 * a12 + a21 * a22;
    const float q = (b00 + b11 + b22) * (1.f / 3.f);
    const float p1 = b01 * b01 + b02 * b02 + b12 * b12;
    const float d0 = b00 - q, d1 = b11 - q, d2 = b22 - q;
    const float p2 = d0 * d0 + d1 * d1 + d2 * d2 + 2.f * p1;
    float e1, e2, e3;
    if (p2 < 1e-20f) {
      e1 = e2 = e3 = q;
    } else {
      const float pp = sqrtf(p2 * (1.f / 6.f));
      const float inv = 1.f / pp;
      const float c00 = d0 * inv, c11 = d1 * inv, c22 = d2 * inv;
      const float c01 = b01 * inv, c02 = b02 * inv, c12 = b12 * inv;
      float r = 0.5f * (c00 * (c11 * c22 - c12 * c12)
                      - c01 * (c01 * c22 - c12 * c02)
                      + c02 * (c01 * c12 - c11 * c02));
      r = fminf(1.f, fmaxf(-1.f, r));
      const float phi = acosf(r) * (1.f / 3.f);
      e1 = q + 2.f * pp * cosf(phi);
      e3 = q + 2.f * pp * cosf(phi + 2.0943951023931953f);
      e2 = 3.f * q - e1 - e3;
    }
    const float s1 = sqrtf(fmaxf(e1, 0.f));
    const float s2 = sqrtf(fmaxf(e2, 0.f));
    const float s3 = sqrtf(fmaxf(e3, 0.f));
    const float dsign = (det > 0.f) ? 1.f : ((det < 0.f) ? -1.f : 0.f);
    const float trRS = s1 + s2 + dsign * s3;
    const float msd = (Ep + Ec - 2.f * trRS) * invN;
    rmsd_out[b] = sqrtf(fmaxf(msd, 0.f));
  }
}

// Reduce B per-batch RMSDs -> mean, single block.
__global__ __launch_bounds__(BLOCK) void mean_kernel(
    const float* __restrict__ rmsd, float* __restrict__ out, int B) {
  float s = 0.f;
  for (int i = threadIdx.x; i < B; i += BLOCK) s += rmsd[i];
#pragma unroll
  for (int off = 32; off > 0; off >>= 1) s += __shfl_down(s, off);
  __shared__ float sm[BLOCK / 64];
  const int wave = threadIdx.x >> 6, lane = threadIdx.x & 63;
  if (lane == 0) sm[wave] = s;
  __syncthreads();
  if (threadIdx.x == 0) {
    float tot = 0.f;
    for (int w = 0; w < BLOCK / 64; w++) tot += sm[w];
    out[0] = tot / (float)B;
  }
}

extern "C" void kernel_launch(void* const* d_in, const int* in_sizes, int n_in,
                              void* d_out, int out_size, void* d_ws, size_t ws_size,
                              hipStream_t stream) {
  const float* P = (const float*)d_in[0];
  const float* C = (const float*)d_in[1];
  float* out = (float*)d_out;
  float* ws = (float*)d_ws;  // B floats of per-batch RMSD
  const int B = in_sizes[0] / (NPTS * 3);
  kabsch_kernel<<<B, BLOCK, 0, stream>>>(P, C, ws, B);
  mean_kernel<<<1, BLOCK, 0, stream>>>(ws, out, B);
}